// Round 4
// baseline (225.982 us; speedup 1.0000x reference)
//
#include <hip/hip_runtime.h>

// Per-row exact top-k (k=1433 of N=2048) mask: out = adj * mask.
// One 256-thread block per row; 8 elems/thread in registers.
// Round 3 (resubmit after broker timeout): single 12-bit MSB radix pass
// (4096 bins; bank-entropy ~4.9 bits on normal data -> near-conflict-free
// atomics), XOR-swizzled uint4 zero/sum, then compact the crossing-bin
// survivors (~20-50) into the dead histogram array and resolve the remaining
// 20 bits with a single-wave ballot radix. Generic chunked ballot covers any
// tie/degenerate row exactly (stable, lowest-index-first, matching
// jax.lax.top_k).

static constexpr int ROW_N   = 2048;
static constexpr int K_KEEP  = 1433;   // max(1, int(2048 * (1.0 - 0.3)))
static constexpr int THREADS = 256;
static constexpr int EPT     = 8;
static constexpr int NB0     = 12;              // first-digit bits
static constexpr int BINS0   = 1 << NB0;        // 4096
static constexpr int BPT0    = BINS0 / THREADS; // 16 bins/thread
static constexpr int SH0     = 32 - NB0;        // 20 remaining bits
static constexpr unsigned LOWMASK = (1u << SH0) - 1u;

struct Smem {
    alignas(16) unsigned hist[BINS0];  // histogram; reused as compact array
    unsigned wtot[4];
    unsigned bc_bin, bc_krem, bc_cnt;
    unsigned cctr;
    unsigned r_tu, r_krem, r_cnteq;
};

// Order-preserving fp32 -> uint mapping (larger float => larger uint)
__device__ __forceinline__ unsigned ord_f32(unsigned b) {
    unsigned m = (unsigned)((int)b >> 31);
    return b ^ (m | 0x80000000u);
}

__global__ __launch_bounds__(THREADS)
void topk_row_mask(const float* __restrict__ in, float* __restrict__ out) {
    __shared__ Smem sm;
    const int row  = blockIdx.x;
    const int t    = threadIdx.x;
    const int lane = t & 63;
    const int w    = t >> 6;
    const int xr   = (t >> 1) & 3;   // quad swizzle for this thread's 16 bins

    const float4* rin  = reinterpret_cast<const float4*>(in)  + (size_t)row * (ROW_N / 4);
    float4*       rout = reinterpret_cast<float4*>(out)       + (size_t)row * (ROW_N / 4);

    const float4 va = rin[t * 2 + 0];
    const float4 vb = rin[t * 2 + 1];

    unsigned u[EPT];
    u[0] = ord_f32(__float_as_uint(va.x));
    u[1] = ord_f32(__float_as_uint(va.y));
    u[2] = ord_f32(__float_as_uint(va.z));
    u[3] = ord_f32(__float_as_uint(va.w));
    u[4] = ord_f32(__float_as_uint(vb.x));
    u[5] = ord_f32(__float_as_uint(vb.y));
    u[6] = ord_f32(__float_as_uint(vb.z));
    u[7] = ord_f32(__float_as_uint(vb.w));

    // ---- zero histogram (swizzled uint4 -> uniform bank load) ----
    {
        uint4* hq = reinterpret_cast<uint4*>(sm.hist);
        const uint4 z = make_uint4(0u, 0u, 0u, 0u);
        #pragma unroll
        for (int i = 0; i < 4; ++i) hq[t * 4 + (i ^ xr)] = z;
        if (t == 0) sm.cctr = 0u;
    }
    __syncthreads();                                           // B1

    // ---- 12-bit histogram; phys = g ^ ((g>>3)&0xC) matches the quad swizzle
    #pragma unroll
    for (int i = 0; i < EPT; ++i) {
        unsigned g = u[i] >> SH0;
        atomicAdd(&sm.hist[g ^ ((g >> 3) & 0xCu)], 1u);
    }
    __syncthreads();                                           // B2

    // ---- per-thread bin total (swizzled uint4 reads) ----
    unsigned T = 0;
    {
        uint4* hq = reinterpret_cast<uint4*>(sm.hist);
        #pragma unroll
        for (int i = 0; i < 4; ++i) {
            uint4 x = hq[t * 4 + (i ^ xr)];
            T += x.x + x.y + x.z + x.w;
        }
    }

    // ---- wave suffix-inclusive scan of T, then inter-wave via wtot ----
    unsigned s = T;
    #pragma unroll
    for (int d = 1; d < 64; d <<= 1) {
        unsigned o = __shfl_down(s, d);
        s += (lane + d < 64) ? o : 0u;
    }
    if (lane == 0) sm.wtot[w] = s;
    __syncthreads();                                           // B3

    unsigned later = 0;
    #pragma unroll
    for (int w2 = 1; w2 < 4; ++w2) later += (w2 > w) ? sm.wtot[w2] : 0u;
    const unsigned Sabove = (s - T) + later;   // sum of bins strictly above my range

    // ---- only the unique crossing thread sweeps its 16 bins ----
    if (Sabove < K_KEEP && Sabove + T >= K_KEEP) {
        unsigned Snext = Sabove;
        for (int i = BPT0 - 1; i >= 0; --i) {
            unsigned phys = (unsigned)(t * BPT0) + ((((unsigned)(i >> 2) ^ (unsigned)xr) << 2) | (unsigned)(i & 3));
            unsigned hb = sm.hist[phys];
            unsigned S = Snext + hb;
            if (S >= K_KEEP && Snext < K_KEEP) {
                sm.bc_bin  = (unsigned)(t * BPT0 + i);
                sm.bc_krem = (unsigned)K_KEEP - Snext;
                sm.bc_cnt  = hb;
            }
            Snext = S;
        }
    }
    __syncthreads();                                           // B4

    const unsigned b    = sm.bc_bin;
    const unsigned krem = sm.bc_krem;
    const unsigned cnt  = sm.bc_cnt;

    // ---- compact crossing-bin survivors (low 20 bits) into dead hist ----
    #pragma unroll
    for (int i = 0; i < EPT; ++i) {
        if ((u[i] >> SH0) == b) {
            unsigned p = atomicAdd(&sm.cctr, 1u);
            sm.hist[p] = u[i] & LOWMASK;
        }
    }
    __syncthreads();                                           // B5

    // ---- wave 0: ballot-radix over the remaining 20 bits ----
    if (w == 0) {
        if (cnt <= 64u) {
            unsigned v = (lane < (int)cnt) ? sm.hist[lane] : 0u;
            bool act = (lane < (int)cnt);
            unsigned kr = krem;
            #pragma unroll
            for (int bpos = SH0 - 1; bpos >= 0; --bpos) {
                bool bitset = ((v >> bpos) & 1u) != 0u;
                bool pb = act && bitset;
                unsigned c = (unsigned)__popcll(__ballot(pb));
                if (c >= kr) {
                    act = pb;
                } else {
                    kr -= c;
                    act = act && !bitset;
                }
            }
            unsigned long long eq = __ballot(act);
            unsigned cnteq = (unsigned)__popcll(eq);
            int fl = __ffsll(eq) - 1;              // eq != 0 guaranteed
            unsigned tl = __shfl(v, fl);
            if (lane == 0) {
                sm.r_tu    = (b << SH0) | tl;
                sm.r_krem  = kr;
                sm.r_cnteq = cnteq;
            }
        } else {
            // rare: >64 survivors (heavy ties) — chunked ballot, exact
            unsigned kr  = krem;
            unsigned pfx = 0u;
            const int nc = ((int)cnt + 63) >> 6;
            for (int bpos = SH0 - 1; bpos >= 0; --bpos) {
                unsigned c = 0;
                for (int base = 0; base < nc; ++base) {
                    int idx = base * 64 + lane;
                    unsigned v = (idx < (int)cnt) ? sm.hist[idx] : 0u;
                    bool p = (idx < (int)cnt) &&
                             ((v >> (bpos + 1)) == (pfx >> (bpos + 1))) &&
                             (((v >> bpos) & 1u) != 0u);
                    c += (unsigned)__popcll(__ballot(p));
                }
                if (c >= kr) pfx |= (1u << bpos);
                else         kr  -= c;
            }
            unsigned cnteq = 0;
            for (int base = 0; base < nc; ++base) {
                int idx = base * 64 + lane;
                bool p = (idx < (int)cnt) && (sm.hist[idx] == pfx);
                cnteq += (unsigned)__popcll(__ballot(p));
            }
            if (lane == 0) {
                sm.r_tu    = (b << SH0) | pfx;
                sm.r_krem  = kr;
                sm.r_cnteq = cnteq;
            }
        }
    }
    __syncthreads();                                           // B6

    const unsigned tu    = sm.r_tu;
    const unsigned kq    = sm.r_krem;    // equals to keep
    const unsigned cnteq = sm.r_cnteq;   // total equals

    if (kq == cnteq) {
        // keep = (u >= tu); no tie ranking needed
        float4 oa, ob;
        oa.x = (u[0] >= tu) ? va.x : 0.0f;
        oa.y = (u[1] >= tu) ? va.y : 0.0f;
        oa.z = (u[2] >= tu) ? va.z : 0.0f;
        oa.w = (u[3] >= tu) ? va.w : 0.0f;
        ob.x = (u[4] >= tu) ? vb.x : 0.0f;
        ob.y = (u[5] >= tu) ? vb.y : 0.0f;
        ob.z = (u[6] >= tu) ? vb.z : 0.0f;
        ob.w = (u[7] >= tu) ? vb.w : 0.0f;
        rout[t * 2 + 0] = oa;
        rout[t * 2 + 1] = ob;
    } else {
        // rare: stable rank among equals, lowest index first, keep kq of them
        unsigned ce = 0;
        #pragma unroll
        for (int i = 0; i < EPT; ++i) ce += (u[i] == tu) ? 1u : 0u;

        unsigned s2 = ce;          // wave inclusive scan (index order)
        #pragma unroll
        for (int d = 1; d < 64; d <<= 1) {
            unsigned o = __shfl_up(s2, d);
            s2 += (lane >= d) ? o : 0u;
        }
        if (lane == 63) sm.wtot[w] = s2;
        __syncthreads();
        unsigned basew = 0;
        #pragma unroll
        for (int w2 = 0; w2 < 3; ++w2) basew += (w2 < w) ? sm.wtot[w2] : 0u;
        unsigned rank = basew + s2 - ce;

        const float orig[EPT] = {va.x, va.y, va.z, va.w, vb.x, vb.y, vb.z, vb.w};
        float ov[EPT];
        #pragma unroll
        for (int i = 0; i < EPT; ++i) {
            bool keep;
            if (u[i] > tu) {
                keep = true;
            } else if (u[i] == tu) {
                keep = (rank < kq);
                rank++;
            } else {
                keep = false;
            }
            ov[i] = keep ? orig[i] : 0.0f;
        }
        rout[t * 2 + 0] = make_float4(ov[0], ov[1], ov[2], ov[3]);
        rout[t * 2 + 1] = make_float4(ov[4], ov[5], ov[6], ov[7]);
    }
}

extern "C" void kernel_launch(void* const* d_in, const int* in_sizes, int n_in,
                              void* d_out, int out_size, void* d_ws, size_t ws_size,
                              hipStream_t stream) {
    const float* in  = (const float*)d_in[0];
    float*       out = (float*)d_out;
    const int rows = in_sizes[0] / ROW_N;   // 8 * 2048 = 16384
    hipLaunchKernelGGL(topk_row_mask, dim3(rows), dim3(THREADS), 0, stream, in, out);
}

// Round 8
// 225.197 us; speedup vs baseline: 1.0035x; 1.0035x over previous
//
#include <hip/hip_runtime.h>

// Per-row exact top-k (k=1433 of N=2048) mask: out = adj * mask.
// Round 5 (3rd resubmit after broker timeouts): the LDS pipe (not VALU, not
// bank conflicts) was the ~83%-occupied resource. Replace the 4096-bin LDS
// histogram with distribution-aware bracket counting: ballot-count x >= T_HI
// (no LDS), slice-histogram only the ~276 elements in [T_LO, T_HI) into 64
// bins, wave0 resolves the crossing slice's ~5 survivors with a 32-bit ballot
// radix. Exact for ANY data via a block-uniform fallback (full dump + chunked
// ballot radix); the bracket is ~6.5 count-sigmas wide so the fallback fires
// with prob ~1e-11 per row on N(0,1) inputs. Stable ties (lowest index first)
// exactly as jax.lax.top_k.

static constexpr int ROW_N   = 2048;
static constexpr int K_KEEP  = 1433;   // max(1, int(2048 * (1.0 - 0.3)))
static constexpr int THREADS = 256;
static constexpr int EPT     = 8;
static constexpr int NSLICE  = 64;

static constexpr float T_LO      = -0.72f;         // P(x>=T_LO)*2048 ~ 1565 > k
static constexpr float T_HI      = -0.33f;         // P(x>=T_HI)*2048 ~ 1289 < k
static constexpr float SLICE_INV = 164.1025641f;   // NSLICE / (T_HI - T_LO)

struct Smem {
    unsigned hist[NSLICE];
    unsigned wcnt[4];                  // per-wave count of x >= T_HI
    unsigned wtot[4];                  // rare tie-ranking scan
    unsigned cctr;
    unsigned r_slice, r_krem, r_flag;
    unsigned r_tu, r_kq, r_cnteq;
    alignas(16) unsigned slotbuf[ROW_N];   // survivors (common) / full dump (fallback)
};

// Order-preserving fp32 -> uint mapping (larger float => larger uint)
__device__ __forceinline__ unsigned ord_f32(unsigned b) {
    unsigned m = (unsigned)((int)b >> 31);
    return b ^ (m | 0x80000000u);
}

// Monotone non-decreasing in x for x >= T_LO (fp rounding is monotone).
__device__ __forceinline__ unsigned slice_idx(float x) {
    int i = (int)((x - T_LO) * SLICE_INV);
    return (unsigned)((i > NSLICE - 1) ? NSLICE - 1 : i);
}

__global__ __launch_bounds__(THREADS)
void topk_row_mask(const float* __restrict__ in, float* __restrict__ out) {
    __shared__ Smem sm;
    const int row  = blockIdx.x;
    const int t    = threadIdx.x;
    const int lane = t & 63;
    const int w    = t >> 6;

    const float4* rin  = reinterpret_cast<const float4*>(in)  + (size_t)row * (ROW_N / 4);
    float4*       rout = reinterpret_cast<float4*>(out)       + (size_t)row * (ROW_N / 4);

    const float4 va = rin[t * 2 + 0];
    const float4 vb = rin[t * 2 + 1];

    const float x[EPT] = {va.x, va.y, va.z, va.w, vb.x, vb.y, vb.z, vb.w};
    unsigned u[EPT];
    #pragma unroll
    for (int i = 0; i < EPT; ++i) u[i] = ord_f32(__float_as_uint(x[i]));

    if (t < NSLICE) sm.hist[t] = 0u;
    if (t == 0)     sm.cctr = 0u;
    __syncthreads();                                           // B1

    // ---- count x >= T_HI via ballots (no LDS traffic) ----
    unsigned wc = 0;
    #pragma unroll
    for (int i = 0; i < EPT; ++i)
        wc += (unsigned)__popcll(__ballot(x[i] >= T_HI));
    if (lane == 0) sm.wcnt[w] = wc;

    // ---- slice-histogram only the in-bracket elements (~276 per row) ----
    #pragma unroll
    for (int i = 0; i < EPT; ++i) {
        if (x[i] >= T_LO && x[i] < T_HI)
            atomicAdd(&sm.hist[slice_idx(x[i])], 1u);
    }
    __syncthreads();                                           // B2

    // ---- wave 0: suffix scan of 64 slices, find crossing ----
    if (w == 0) {
        const unsigned Chi = sm.wcnt[0] + sm.wcnt[1] + sm.wcnt[2] + sm.wcnt[3];
        const unsigned h = sm.hist[lane];
        unsigned s = h;
        #pragma unroll
        for (int d = 1; d < 64; d <<= 1) {
            unsigned o = __shfl_down(s, d);
            s += (lane + d < 64) ? o : 0u;
        }
        const unsigned Sl = Chi + s;       // #elements >= lower edge of my slice
        const unsigned Sn = Sl - h;        // #elements >= upper edge
        if (Sl >= (unsigned)K_KEEP && Sn < (unsigned)K_KEEP) {
            sm.r_slice = (unsigned)lane;
            sm.r_krem  = (unsigned)K_KEEP - Sn;
        }
        if (lane == 0)
            sm.r_flag = (Chi < (unsigned)K_KEEP && (unsigned)K_KEEP <= Chi + s) ? 0u : 1u;
    }
    __syncthreads();                                           // B3

    const unsigned flag = sm.r_flag;
    if (flag == 0u) {
        // ---- compact crossing-slice survivors (~5) ----
        const unsigned sl = sm.r_slice;
        #pragma unroll
        for (int i = 0; i < EPT; ++i) {
            if (x[i] >= T_LO && x[i] < T_HI && slice_idx(x[i]) == sl) {
                unsigned p = atomicAdd(&sm.cctr, 1u);
                sm.slotbuf[p] = u[i];
            }
        }
    } else {
        // ---- fallback (bracket missed / degenerate data): dump everything
        uint4* sb = reinterpret_cast<uint4*>(sm.slotbuf);
        sb[t * 2 + 0] = make_uint4(u[0], u[1], u[2], u[3]);
        sb[t * 2 + 1] = make_uint4(u[4], u[5], u[6], u[7]);
    }
    __syncthreads();                                           // B4

    const unsigned cnt = (flag == 0u) ? sm.cctr   : (unsigned)ROW_N;
    const unsigned kr0 = (flag == 0u) ? sm.r_krem : (unsigned)K_KEEP;

    // ---- wave 0: exact threshold among survivors via 32-bit ballot radix ----
    if (w == 0) {
        if (cnt <= 64u) {
            unsigned v = (lane < (int)cnt) ? sm.slotbuf[lane] : 0u;
            bool act = (lane < (int)cnt);
            unsigned kr = kr0;
            for (int bpos = 31; bpos >= 0; --bpos) {
                bool bitset = ((v >> bpos) & 1u) != 0u;
                bool pb = act && bitset;
                unsigned c = (unsigned)__popcll(__ballot(pb));
                if (c >= kr) {
                    act = pb;
                } else {
                    kr -= c;
                    act = act && !bitset;
                }
            }
            unsigned long long eq = __ballot(act);
            unsigned cnteq = (unsigned)__popcll(eq);
            int fl = __ffsll(eq) - 1;              // eq != 0 guaranteed
            unsigned tl = __shfl(v, fl);
            if (lane == 0) {
                sm.r_tu    = tl;
                sm.r_kq    = kr;
                sm.r_cnteq = cnteq;
            }
        } else {
            // chunked ballot radix (fallback path / heavy ties), exact
            unsigned kr = kr0, pfx = 0u;
            const int nc = ((int)cnt + 63) >> 6;
            for (int bpos = 31; bpos >= 0; --bpos) {
                unsigned c = 0;
                for (int base = 0; base < nc; ++base) {
                    int idx = base * 64 + lane;
                    unsigned v = (idx < (int)cnt) ? sm.slotbuf[idx] : 0u;
                    // agree-above-bpos test, shift-safe for bpos=31:
                    bool p = (idx < (int)cnt) &&
                             ((((v ^ pfx) >> bpos) >> 1) == 0u) &&
                             (((v >> bpos) & 1u) != 0u);
                    c += (unsigned)__popcll(__ballot(p));
                }
                if (c >= kr) pfx |= (1u << bpos);
                else         kr  -= c;
            }
            unsigned cnteq = 0;
            for (int base = 0; base < nc; ++base) {
                int idx = base * 64 + lane;
                bool p = (idx < (int)cnt) && (sm.slotbuf[idx] == pfx);
                cnteq += (unsigned)__popcll(__ballot(p));
            }
            if (lane == 0) {
                sm.r_tu    = pfx;
                sm.r_kq    = kr;
                sm.r_cnteq = cnteq;
            }
        }
    }
    __syncthreads();                                           // B5

    const unsigned tu    = sm.r_tu;
    const unsigned kq    = sm.r_kq;      // equals to keep
    const unsigned cnteq = sm.r_cnteq;   // total equals

    if (kq == cnteq) {
        // keep = (u >= tu); no tie ranking needed
        float4 oa, ob;
        oa.x = (u[0] >= tu) ? x[0] : 0.0f;
        oa.y = (u[1] >= tu) ? x[1] : 0.0f;
        oa.z = (u[2] >= tu) ? x[2] : 0.0f;
        oa.w = (u[3] >= tu) ? x[3] : 0.0f;
        ob.x = (u[4] >= tu) ? x[4] : 0.0f;
        ob.y = (u[5] >= tu) ? x[5] : 0.0f;
        ob.z = (u[6] >= tu) ? x[6] : 0.0f;
        ob.w = (u[7] >= tu) ? x[7] : 0.0f;
        rout[t * 2 + 0] = oa;
        rout[t * 2 + 1] = ob;
    } else {
        // rare: stable rank among equals, lowest index first, keep kq of them
        unsigned ce = 0;
        #pragma unroll
        for (int i = 0; i < EPT; ++i) ce += (u[i] == tu) ? 1u : 0u;

        unsigned s2 = ce;          // wave inclusive scan (index order)
        #pragma unroll
        for (int d = 1; d < 64; d <<= 1) {
            unsigned o = __shfl_up(s2, d);
            s2 += (lane >= d) ? o : 0u;
        }
        if (lane == 63) sm.wtot[w] = s2;
        __syncthreads();
        unsigned basew = 0;
        #pragma unroll
        for (int w2 = 0; w2 < 3; ++w2) basew += (w2 < w) ? sm.wtot[w2] : 0u;
        unsigned rank = basew + s2 - ce;

        float ov[EPT];
        #pragma unroll
        for (int i = 0; i < EPT; ++i) {
            bool keep;
            if (u[i] > tu) {
                keep = true;
            } else if (u[i] == tu) {
                keep = (rank < kq);
                rank++;
            } else {
                keep = false;
            }
            ov[i] = keep ? x[i] : 0.0f;
        }
        rout[t * 2 + 0] = make_float4(ov[0], ov[1], ov[2], ov[3]);
        rout[t * 2 + 1] = make_float4(ov[4], ov[5], ov[6], ov[7]);
    }
}

extern "C" void kernel_launch(void* const* d_in, const int* in_sizes, int n_in,
                              void* d_out, int out_size, void* d_ws, size_t ws_size,
                              hipStream_t stream) {
    const float* in  = (const float*)d_in[0];
    float*       out = (float*)d_out;
    const int rows = in_sizes[0] / ROW_N;   // 8 * 2048 = 16384
    hipLaunchKernelGGL(topk_row_mask, dim3(rows), dim3(THREADS), 0, stream, in, out);
}